// Round 12
// baseline (2439.734 us; speedup 1.0000x reference)
//
#include <hip/hip_runtime.h>
#include <hip/hip_fp16.h>

#define ALPHA 0.5f
#define BSH 9            // bucket shift: 512 nodes/bucket
#define BSZ 512          // nodes per bucket
#define MAXB 512         // max buckets -> supports N <= 262144
#define CHUNK 4096       // edges per block in bucket_scatter
#define PG 256           // max graphs held in LDS pool (G == 256 here)
#define PXB 128          // x-blocks in scatter_pool

static inline int ceil_div(int a, int b) { return (a + b - 1) / b; }

typedef _Float16 half8 __attribute__((ext_vector_type(8)));
typedef float f32x4 __attribute__((ext_vector_type(4)));

// ---------------- bucket histogram (both directions) ----------------
__global__ void hist_kernel(const int* __restrict__ src, const int* __restrict__ dst,
                            unsigned int* __restrict__ bhI, unsigned int* __restrict__ bhO,
                            int E, int nbuck)
{
    __shared__ unsigned int hI[MAXB], hO[MAXB];
    for (int b = threadIdx.x; b < MAXB; b += blockDim.x) { hI[b] = 0; hO[b] = 0; }
    __syncthreads();
    for (int e = blockIdx.x * blockDim.x + threadIdx.x; e < E; e += gridDim.x * blockDim.x) {
        atomicAdd(&hI[dst[e] >> BSH], 1u);
        atomicAdd(&hO[src[e] >> BSH], 1u);
    }
    __syncthreads();
    for (int b = threadIdx.x; b < nbuck; b += blockDim.x) {
        if (hI[b]) atomicAdd(&bhI[b], hI[b]);
        if (hO[b]) atomicAdd(&bhO[b], hO[b]);
    }
}

// ---------------- bucket bases: exclusive scan of both hists (1 block, MAXB threads) ------
__global__ void bucket_base_kernel(const unsigned int* __restrict__ bhI,
                                   const unsigned int* __restrict__ bhO,
                                   unsigned int* __restrict__ baseI, unsigned int* __restrict__ baseO,
                                   unsigned int* __restrict__ curI, unsigned int* __restrict__ curO,
                                   int nbuck)
{
    __shared__ unsigned int tI[MAXB], tO[MAXB];
    int t = threadIdx.x;
    unsigned int vI = (t < nbuck) ? bhI[t] : 0u;
    unsigned int vO = (t < nbuck) ? bhO[t] : 0u;
    tI[t] = vI; tO[t] = vO;
    __syncthreads();
    for (int o = 1; o < MAXB; o <<= 1) {
        unsigned int xI = (t >= o) ? tI[t - o] : 0u;
        unsigned int xO = (t >= o) ? tO[t - o] : 0u;
        __syncthreads();
        tI[t] += xI; tO[t] += xO;
        __syncthreads();
    }
    if (t < nbuck) {
        baseI[t] = tI[t] - vI; baseO[t] = tO[t] - vO;
        curI[t]  = tI[t] - vI; curO[t]  = tO[t] - vO;
    }
}

// ---------------- bucket scatter with block-local reservation ----------------
__global__ void bucket_scatter_kernel(const int* __restrict__ src, const int* __restrict__ dst,
                                      unsigned int* __restrict__ curI, unsigned int* __restrict__ curO,
                                      int2* __restrict__ ebI, int2* __restrict__ ebO, int E)
{
    __shared__ unsigned int cI[MAXB], cO[MAXB], bI[MAXB], bO[MAXB];
    int t = threadIdx.x;
    for (int b = t; b < MAXB; b += blockDim.x) { cI[b] = 0; cO[b] = 0; }
    __syncthreads();
    int e0 = blockIdx.x * CHUNK;
    int e1 = min(E, e0 + CHUNK);
    for (int e = e0 + t; e < e1; e += blockDim.x) {
        atomicAdd(&cI[dst[e] >> BSH], 1u);
        atomicAdd(&cO[src[e] >> BSH], 1u);
    }
    __syncthreads();
    for (int b = t; b < MAXB; b += blockDim.x) {
        unsigned int n = cI[b];
        if (n) bI[b] = atomicAdd(&curI[b], n);
        cI[b] = 0;
        n = cO[b];
        if (n) bO[b] = atomicAdd(&curO[b], n);
        cO[b] = 0;
    }
    __syncthreads();
    for (int e = e0 + t; e < e1; e += blockDim.x) {
        int s = src[e], d = dst[e];
        int lb = d >> BSH;
        unsigned int p = bI[lb] + atomicAdd(&cI[lb], 1u);
        ebI[p] = make_int2(d, s);
        lb = s >> BSH;
        p = bO[lb] + atomicAdd(&cO[lb], 1u);
        ebO[p] = make_int2(s, d);
    }
}

// ---------------- fused per-bucket CSR finalize: deg + scan + rowstart/dinv + adj --------
__global__ __launch_bounds__(256) void bucket_csr_kernel(
    const int2* __restrict__ ebI, const int2* __restrict__ ebO,
    const unsigned int* __restrict__ baseI, const unsigned int* __restrict__ baseO,
    const unsigned int* __restrict__ bendI, const unsigned int* __restrict__ bendO,
    unsigned int* __restrict__ rowI, unsigned int* __restrict__ rowO,
    unsigned int* __restrict__ degI, unsigned int* __restrict__ degO,
    float* __restrict__ dinvI, float* __restrict__ dinvO,
    int* __restrict__ adjI, int* __restrict__ adjO, int N)
{
    const int2* __restrict__ eb           = blockIdx.y ? ebO : ebI;
    const unsigned int* __restrict__ base = blockIdx.y ? baseO : baseI;
    const unsigned int* __restrict__ bend = blockIdx.y ? bendO : bendI;
    unsigned int* __restrict__ row        = blockIdx.y ? rowO : rowI;
    unsigned int* __restrict__ deg        = blockIdx.y ? degO : degI;
    float* __restrict__ dinv              = blockIdx.y ? dinvO : dinvI;
    int* __restrict__ adj                 = blockIdx.y ? adjO : adjI;

    __shared__ unsigned int d[BSZ];
    __shared__ unsigned int ex[BSZ];
    __shared__ unsigned int ps[256];
    int b = blockIdx.x, t = threadIdx.x;
    int nbase = b << BSH;

    for (int i = t; i < BSZ; i += 256) d[i] = 0;
    __syncthreads();
    unsigned int lo = base[b], hi = bend[b];
    for (unsigned int i = lo + t; i < hi; i += 256)
        atomicAdd(&d[eb[i].x - nbase], 1u);
    __syncthreads();

    ps[t] = d[2 * t] + d[2 * t + 1];
    __syncthreads();
    for (int o = 1; o < 256; o <<= 1) {
        unsigned int x = (t >= o) ? ps[t - o] : 0u;
        __syncthreads();
        ps[t] += x;
        __syncthreads();
    }
    unsigned int p0 = (t > 0) ? ps[t - 1] : 0u;
    ex[2 * t]     = p0;
    ex[2 * t + 1] = p0 + d[2 * t];
    __syncthreads();

    for (int i = t; i < BSZ; i += 256) {
        int v = nbase + i;
        if (v < N) {
            unsigned int dd = d[i];
            row[v]  = lo + ex[i];
            deg[v]  = dd;
            dinv[v] = dd ? rsqrtf((float)dd) : 0.f;
        }
    }
    __syncthreads();
    for (int i = t; i < BSZ; i += 256) d[i] = lo + ex[i];
    __syncthreads();
    for (unsigned int i = lo + t; i < hi; i += 256) {
        int2 e = eb[i];
        unsigned int p = atomicAdd(&d[e.x - nbase], 1u);
        adj[p] = e.y;
    }
}

// ---------------- per-graph node counts via binary search (seg is sorted) ----------------
__global__ void seg_cnt_kernel(const int* __restrict__ seg, float* __restrict__ cnt, int N, int G)
{
    int g = blockIdx.x * blockDim.x + threadIdx.x;
    if (g >= G) return;
    int lo = 0, hi = N;
    while (lo < hi) { int m = (lo + hi) >> 1; if (seg[m] < g) lo = m + 1; else hi = m; }
    int s0 = lo;
    hi = N;
    while (lo < hi) { int m = (lo + hi) >> 1; if (seg[m] < g + 1) lo = m + 1; else hi = m; }
    cnt[g] = (float)(lo - s0);
}

// ---------------- layer2 weight prep: Wt[j][k] fp16 (pre-scaled, transposed), bcomb ------
__global__ void prep_w_kernel(const float* __restrict__ Wi, const float* __restrict__ Wr,
                              const float* __restrict__ bi, const float* __restrict__ br,
                              __half* __restrict__ Wt, float* __restrict__ bcomb)
{
    int idx = blockIdx.x * 256 + threadIdx.x;   // 128*256 elems
    if (idx < 128 * 256) {
        int j = idx >> 8, k = idx & 255;
        float w = (k < 128) ? (1.f - ALPHA) * Wi[k * 128 + j]
                            : ALPHA * Wr[(k - 128) * 128 + j];
        Wt[idx] = __float2half_rn(w);           // Wt[j*256 + k]
    }
    if (idx < 128) bcomb[idx] = (1.f - ALPHA) * bi[idx] + ALPHA * br[idx];
}

// ---------------- fused layer 1: CSR width-4 gathers + dense 4->128 fp16, relu ----------
__global__ __launch_bounds__(256) void layer1_fused_kernel(
    const unsigned int* __restrict__ rowI, const unsigned int* __restrict__ degI,
    const int* __restrict__ adjI, const float* __restrict__ dinvI,
    const unsigned int* __restrict__ rowO, const unsigned int* __restrict__ degO,
    const int* __restrict__ adjO, const float* __restrict__ dinvO,
    const float4* __restrict__ x4,
    const float* __restrict__ Wi, const float* __restrict__ bi,
    const float* __restrict__ Wr, const float* __restrict__ br,
    __half* __restrict__ h1, int N)
{
    __shared__ float wI[4][128], wO[4][128], bb[128];
    int t = threadIdx.x;
    if (t < 128) {
#pragma unroll
        for (int c = 0; c < 4; ++c) {
            wI[c][t] = (1.f - ALPHA) * Wi[c * 128 + t];
            wO[c][t] = ALPHA * Wr[c * 128 + t];
        }
        bb[t] = (1.f - ALPHA) * bi[t] + ALPHA * br[t];
    }
    __syncthreads();
    int v = blockIdx.x * 256 + t;
    if (v >= N) return;

    float4 aI = {0.f, 0.f, 0.f, 0.f};
    {
        unsigned int k = rowI[v], end = k + degI[v];
        for (; k < end; ++k) {
            int s = adjI[k];
            float w = dinvI[s];
            float4 xv = x4[s];
            aI.x += w * xv.x; aI.y += w * xv.y; aI.z += w * xv.z; aI.w += w * xv.w;
        }
        float dv = dinvI[v];
        aI.x *= dv; aI.y *= dv; aI.z *= dv; aI.w *= dv;
    }
    float4 aO = {0.f, 0.f, 0.f, 0.f};
    {
        unsigned int k = rowO[v], end = k + degO[v];
        for (; k < end; ++k) {
            int s = adjO[k];
            float w = dinvO[s];
            float4 xv = x4[s];
            aO.x += w * xv.x; aO.y += w * xv.y; aO.z += w * xv.z; aO.w += w * xv.w;
        }
        float dv = dinvO[v];
        aO.x *= dv; aO.y *= dv; aO.z *= dv; aO.w *= dv;
    }

    half8* outp = (half8*)&h1[(size_t)v * 128];
#pragma unroll
    for (int jq = 0; jq < 16; ++jq) {
        half8 o;
#pragma unroll
        for (int u = 0; u < 8; ++u) {
            int j = jq * 8 + u;
            float s = bb[j]
                    + aI.x * wI[0][j] + aI.y * wI[1][j] + aI.z * wI[2][j] + aI.w * wI[3][j]
                    + aO.x * wO[0][j] + aO.y * wO[1][j] + aO.z * wO[2][j] + aO.w * wO[3][j];
            o[u] = (_Float16)fmaxf(s, 0.f);
        }
        outp[jq] = o;
    }
}

// ---------------- CSR gather aggregation (layer 2 only), 16 lanes x half8, unroll 4 ------
__global__ void gather128_kernel(const unsigned int* __restrict__ rowstartI,
                                 const unsigned int* __restrict__ degI,
                                 const int* __restrict__ adjI,
                                 const float* __restrict__ dinvI,
                                 const unsigned int* __restrict__ rowstartO,
                                 const unsigned int* __restrict__ degO,
                                 const int* __restrict__ adjO,
                                 const float* __restrict__ dinvO,
                                 const half8* __restrict__ hp,
                                 half8* __restrict__ outI, half8* __restrict__ outO, int N)
{
    int v = blockIdx.x * 16 + (threadIdx.x >> 4);
    if (v >= N) return;
    int lane = threadIdx.x & 15;
    const unsigned int* __restrict__ rowstart = blockIdx.y ? rowstartO : rowstartI;
    const unsigned int* __restrict__ deg      = blockIdx.y ? degO : degI;
    const int* __restrict__ adj               = blockIdx.y ? adjO : adjI;
    const float* __restrict__ dinv            = blockIdx.y ? dinvO : dinvI;
    half8* __restrict__ out                   = blockIdx.y ? outO : outI;

    unsigned int k = rowstart[v];
    unsigned int end = k + deg[v];
    float acc[8];
#pragma unroll
    for (int i = 0; i < 8; ++i) acc[i] = 0.f;

    for (; k + 4 <= end; k += 4) {
        int s0 = adj[k], s1 = adj[k + 1], s2 = adj[k + 2], s3 = adj[k + 3];
        float w0 = dinv[s0], w1 = dinv[s1], w2 = dinv[s2], w3 = dinv[s3];
        half8 h0 = hp[(size_t)s0 * 16 + lane];
        half8 h1 = hp[(size_t)s1 * 16 + lane];
        half8 h2 = hp[(size_t)s2 * 16 + lane];
        half8 h3 = hp[(size_t)s3 * 16 + lane];
#pragma unroll
        for (int i = 0; i < 8; ++i)
            acc[i] += w0 * (float)h0[i] + w1 * (float)h1[i]
                    + w2 * (float)h2[i] + w3 * (float)h3[i];
    }
    for (; k < end; ++k) {
        int s = adj[k];
        float w = dinv[s];
        half8 hv = hp[(size_t)s * 16 + lane];
#pragma unroll
        for (int i = 0; i < 8; ++i)
            acc[i] += w * (float)hv[i];
    }
    float dv = dinv[v];
    half8 o;
#pragma unroll
    for (int i = 0; i < 8; ++i) o[i] = (_Float16)(dv * acc[i]);
    out[(size_t)v * 16 + lane] = o;
}

// ---------------- layer 2 via MFMA: [aggI|aggO] (N,256)fp16 @ Wt^T -> (N,128) fp16 -------
__global__ __launch_bounds__(256) void layer2_mfma_kernel(
    const __half* __restrict__ aggI, const __half* __restrict__ aggO,   // [N][128] each
    const __half* __restrict__ Wt,    // [128][256] pre-scaled, transposed
    const float* __restrict__ bcomb,  // [128]
    __half* __restrict__ h2, int N)
{
    int wave = threadIdx.x >> 6;
    int lane = threadIdx.x & 63;
    int v0 = blockIdx.x * 64 + wave * 16;
    int row = lane & 15;
    int kg  = lane >> 4;                 // 0..3
    int vsafe = min(v0 + row, N - 1);

    f32x4 acc[8];
#pragma unroll
    for (int t = 0; t < 8; ++t) acc[t] = (f32x4){0.f, 0.f, 0.f, 0.f};

#pragma unroll
    for (int ks = 0; ks < 8; ++ks) {
        const __half* asrc = (ks < 4) ? aggI : aggO;
        int kofs = (ks & 3) * 32 + kg * 8;
        half8 afrag = *(const half8*)&asrc[(size_t)vsafe * 128 + kofs];
        int kw = ks * 32 + kg * 8;
#pragma unroll
        for (int t = 0; t < 8; ++t) {
            int j = t * 16 + row;
            half8 bfrag = *(const half8*)&Wt[(size_t)j * 256 + kw];
            acc[t] = __builtin_amdgcn_mfma_f32_16x16x32_f16(afrag, bfrag, acc[t], 0, 0, 0);
        }
    }

#pragma unroll
    for (int t = 0; t < 8; ++t) {
        int j = t * 16 + row;
        float bj = bcomb[j];
#pragma unroll
        for (int r = 0; r < 4; ++r) {
            int vr = v0 + kg * 4 + r;
            if (vr < N)
                h2[(size_t)vr * 128 + j] = __float2half_rn(fmaxf(acc[t][r] + bj, 0.f));
        }
    }
}

// ---------------- layer 3 fused aggregate+pool: edge-transposed, h2 streamed once --------
// dir 0 (poolI): rows s via out-CSR; pool[seg[d]] += dinvI[s]*dinvI[d]*h2[s]
// dir 1 (poolO): rows d via in-CSR;  pool[seg[s]] += dinvO[d]*dinvO[s]*h2[d]
// 512 threads: channel = t&127, row-subset = t>>7 (4 interleaved); LDS pool G x 128 f32.
__global__ __launch_bounds__(512) void scatter_pool_kernel(
    const unsigned int* __restrict__ rowI, const unsigned int* __restrict__ degI,
    const int* __restrict__ adjI, const float* __restrict__ dinvI,
    const unsigned int* __restrict__ rowO, const unsigned int* __restrict__ degO,
    const int* __restrict__ adjO, const float* __restrict__ dinvO,
    const int* __restrict__ seg, const __half* __restrict__ h2,
    float* __restrict__ partials, int N, int G)
{
    int dir = blockIdx.y;
    const unsigned int* __restrict__ row = dir ? rowI : rowO;
    const unsigned int* __restrict__ deg = dir ? degI : degO;
    const int* __restrict__ adj          = dir ? adjI : adjO;
    const float* __restrict__ dinv       = dir ? dinvO : dinvI;

    __shared__ float pool[PG * 128];
    int t = threadIdx.x;
    int ch = t & 127;
    int sub = t >> 7;                    // 0..3
    for (int i = t; i < PG * 128; i += 512) pool[i] = 0.f;
    __syncthreads();

    int chunk = (N + PXB - 1) / PXB;
    int v0 = blockIdx.x * chunk;
    int v1 = min(N, v0 + chunk);
    for (int v = v0 + sub; v < v1; v += 4) {
        float h = __half2float(h2[(size_t)v * 128 + ch]);
        float dv = dinv[v];
        unsigned int k = row[v], end = k + deg[v];
        for (; k + 2 <= end; k += 2) {
            int u0 = adj[k], u1 = adj[k + 1];
            float c0 = dv * dinv[u0], c1 = dv * dinv[u1];
            int g0 = seg[u0], g1 = seg[u1];
            atomicAdd(&pool[g0 * 128 + ch], c0 * h);
            atomicAdd(&pool[g1 * 128 + ch], c1 * h);
        }
        if (k < end) {
            int u = adj[k];
            atomicAdd(&pool[seg[u] * 128 + ch], dv * dinv[u] * h);
        }
    }
    __syncthreads();
    float* out = partials + ((size_t)dir * PXB + blockIdx.x) * (PG * 128);
    for (int i = t; i < G * 128; i += 512) out[i] = pool[i];
}

// ---------------- reduce partials -> poolI/poolO ----------------
__global__ void pool_reduce_kernel(const float* __restrict__ partials,
                                   float* __restrict__ poolI, float* __restrict__ poolO, int G)
{
    int dir = blockIdx.x / G, g = blockIdx.x % G;
    int ch = threadIdx.x;   // 128
    const float* base = partials + (size_t)dir * PXB * (PG * 128) + g * 128 + ch;
    float s = 0.f;
    for (int b = 0; b < PXB; ++b) s += base[(size_t)b * (PG * 128)];
    (dir ? poolO : poolI)[g * 128 + ch] = s;
}

// ---------------- final: (G,128)x2 -> (G,120) with mean ----------------
__global__ void final_kernel(const float* __restrict__ poolI, const float* __restrict__ poolO,
                             const float* __restrict__ cnt,
                             const float* __restrict__ Wo, const float* __restrict__ bo,
                             const float* __restrict__ Wor, const float* __restrict__ bor,
                             float* __restrict__ out, int G)
{
    int g = blockIdx.x;
    int j = threadIdx.x;  // 120 threads
    if (g >= G || j >= 120) return;
    float acc = 0.f;
    for (int k = 0; k < 128; ++k) {
        acc += poolI[g * 128 + k] * ((1.f - ALPHA) * Wo[k * 120 + j])
             + poolO[g * 128 + k] * (ALPHA * Wor[k * 120 + j]);
    }
    float c = cnt[g];
    float bcomb = (1.f - ALPHA) * bo[j] + ALPHA * bor[j];
    out[g * 120 + j] = (c > 0.f) ? (acc / c + bcomb) : 0.f;
}

extern "C" void kernel_launch(void* const* d_in, const int* in_sizes, int n_in,
                              void* d_out, int out_size, void* d_ws, size_t ws_size,
                              hipStream_t stream)
{
    const float* x      = (const float*)d_in[0];
    const int*   ei     = (const int*)d_in[1];
    const int*   seg    = (const int*)d_in[2];
    const float* W_in   = (const float*)d_in[3];
    const float* b_in   = (const float*)d_in[4];
    const float* W_in_r = (const float*)d_in[5];
    const float* b_in_r = (const float*)d_in[6];
    const float* W_mid  = (const float*)d_in[7];
    const float* b_mid  = (const float*)d_in[8];
    const float* W_mid_r= (const float*)d_in[9];
    const float* b_mid_r= (const float*)d_in[10];
    const float* W_out  = (const float*)d_in[11];
    const float* b_out  = (const float*)d_in[12];
    const float* W_out_r= (const float*)d_in[13];
    const float* b_out_r= (const float*)d_in[14];

    const int N = in_sizes[0] / 4;
    const int E = in_sizes[1] / 2;
    const int G = out_size / 120;
    const int* src = ei;
    const int* dst = ei + E;
    const int NBUCK = ceil_div(N, BSZ);      // <= 512

    // -------- workspace layout (4-byte units) --------
    char* wsb = (char*)d_ws;
    size_t off = 0;
    auto alloc = [&](size_t elems) { void* p = wsb + off * 4; off += elems; return p; };

    unsigned int* bhI   = (unsigned int*)alloc(MAXB);     // zeroed
    unsigned int* bhO   = (unsigned int*)alloc(MAXB);     // zeroed
    size_t zero_elems = off;
    float*        poolI = (float*)alloc((size_t)G * 128); // fully written by reduce
    float*        poolO = (float*)alloc((size_t)G * 128);
    float*        cnt   = (float*)alloc(G);               // fully written by seg_cnt
    unsigned int* baseI = (unsigned int*)alloc(MAXB);
    unsigned int* baseO = (unsigned int*)alloc(MAXB);
    unsigned int* curI  = (unsigned int*)alloc(MAXB);
    unsigned int* curO  = (unsigned int*)alloc(MAXB);
    unsigned int* degI  = (unsigned int*)alloc(N);
    unsigned int* degO  = (unsigned int*)alloc(N);
    float*        dinvI = (float*)alloc(N);
    float*        dinvO = (float*)alloc(N);
    unsigned int* rowI  = (unsigned int*)alloc(N);        // exclusive row starts
    unsigned int* rowO  = (unsigned int*)alloc(N);
    int*          adjI  = (int*)alloc(E);
    int*          adjO  = (int*)alloc(E);
    __half*       Wt    = (__half*)alloc(128 * 256 / 2);  // 32768 halves
    float*        bcomb = (float*)alloc(128);
    off = (off + 3) & ~(size_t)3;                         // 16B align
    __half* hbuf = (__half*)alloc((size_t)N * 64);        // h1 / h2 fp16 (N*128 halves)
    __half* aggI = (__half*)alloc((size_t)N * 64);        // fp16 agg in-direction
    __half* aggO = (__half*)alloc((size_t)N * 64);        // fp16 agg out-direction
    (void)ws_size;

    // Aliases: eb buffers live during build (agg dead); partials live after layer2 (agg dead).
    int2* ebI = (int2*)aggI;
    int2* ebO = (int2*)aggO;
    float* partials = (float*)aggI;   // needs 2*PXB*PG*128*4 = 33.6 MB <= 51.2 MB of aggI+aggO

    hipMemsetAsync(d_ws, 0, zero_elems * 4, stream);

    const int T = 256;
    // ---- binned CSR build ----
    hist_kernel<<<ceil_div(E, T * 16), T, 0, stream>>>(src, dst, bhI, bhO, E, NBUCK);
    bucket_base_kernel<<<1, MAXB, 0, stream>>>(bhI, bhO, baseI, baseO, curI, curO, NBUCK);
    bucket_scatter_kernel<<<ceil_div(E, CHUNK), T, 0, stream>>>(src, dst, curI, curO, ebI, ebO, E);
    bucket_csr_kernel<<<dim3(NBUCK, 2), T, 0, stream>>>(ebI, ebO, baseI, baseO, curI, curO,
                                                        rowI, rowO, degI, degO,
                                                        dinvI, dinvO, adjI, adjO, N);
    seg_cnt_kernel<<<ceil_div(G, T), T, 0, stream>>>(seg, cnt, N, G);
    prep_w_kernel<<<128, 256, 0, stream>>>(W_mid, W_mid_r, b_mid, b_mid_r, Wt, bcomb);

    // ---- layer 1: fused CSR-4 gathers + dense 4->128 (fp16 out) ----
    layer1_fused_kernel<<<ceil_div(N, T), T, 0, stream>>>(
        rowI, degI, adjI, dinvI, rowO, degO, adjO, dinvO,
        (const float4*)x, W_in, b_in, W_in_r, b_in_r, hbuf, N);
    // ---- layer 2: fp16 gather (both dirs) then MFMA GEMM (fp16 out) ----
    gather128_kernel<<<dim3(ceil_div(N, 16), 2), 256, 0, stream>>>(
        rowI, degI, adjI, dinvI, rowO, degO, adjO, dinvO,
        (const half8*)hbuf, (half8*)aggI, (half8*)aggO, N);
    layer2_mfma_kernel<<<ceil_div(N, 64), 256, 0, stream>>>(
        aggI, aggO, Wt, bcomb, hbuf, N);
    // ---- layer 3: fused edge-transposed aggregate+pool (h2 streamed once) ----
    scatter_pool_kernel<<<dim3(PXB, 2), 512, 0, stream>>>(
        rowI, degI, adjI, dinvI, rowO, degO, adjO, dinvO,
        seg, hbuf, partials, N, G);
    pool_reduce_kernel<<<2 * G, 128, 0, stream>>>(partials, poolI, poolO, G);
    final_kernel<<<G, 128, 0, stream>>>(poolI, poolO, cnt,
                                        W_out, b_out, W_out_r, b_out_r, (float*)d_out, G);
}

// Round 13
// 457.047 us; speedup vs baseline: 5.3380x; 5.3380x over previous
//
#include <hip/hip_runtime.h>
#include <hip/hip_fp16.h>

#define ALPHA 0.5f
#define BSH 9            // bucket shift: 512 nodes/bucket
#define BSZ 512          // nodes per bucket
#define MAXB 512         // max buckets -> supports N <= 262144
#define CHUNK 4096       // edges per block in bucket_scatter

static inline int ceil_div(int a, int b) { return (a + b - 1) / b; }

typedef _Float16 half8 __attribute__((ext_vector_type(8)));
typedef float f32x4 __attribute__((ext_vector_type(4)));

// ---------------- bucket histogram (both directions) ----------------
__global__ void hist_kernel(const int* __restrict__ src, const int* __restrict__ dst,
                            unsigned int* __restrict__ bhI, unsigned int* __restrict__ bhO,
                            int E, int nbuck)
{
    __shared__ unsigned int hI[MAXB], hO[MAXB];
    for (int b = threadIdx.x; b < MAXB; b += blockDim.x) { hI[b] = 0; hO[b] = 0; }
    __syncthreads();
    for (int e = blockIdx.x * blockDim.x + threadIdx.x; e < E; e += gridDim.x * blockDim.x) {
        atomicAdd(&hI[dst[e] >> BSH], 1u);
        atomicAdd(&hO[src[e] >> BSH], 1u);
    }
    __syncthreads();
    for (int b = threadIdx.x; b < nbuck; b += blockDim.x) {
        if (hI[b]) atomicAdd(&bhI[b], hI[b]);
        if (hO[b]) atomicAdd(&bhO[b], hO[b]);
    }
}

// ---------------- bucket bases: exclusive scan of both hists (1 block, MAXB threads) ------
__global__ void bucket_base_kernel(const unsigned int* __restrict__ bhI,
                                   const unsigned int* __restrict__ bhO,
                                   unsigned int* __restrict__ baseI, unsigned int* __restrict__ baseO,
                                   unsigned int* __restrict__ curI, unsigned int* __restrict__ curO,
                                   int nbuck)
{
    __shared__ unsigned int tI[MAXB], tO[MAXB];
    int t = threadIdx.x;
    unsigned int vI = (t < nbuck) ? bhI[t] : 0u;
    unsigned int vO = (t < nbuck) ? bhO[t] : 0u;
    tI[t] = vI; tO[t] = vO;
    __syncthreads();
    for (int o = 1; o < MAXB; o <<= 1) {
        unsigned int xI = (t >= o) ? tI[t - o] : 0u;
        unsigned int xO = (t >= o) ? tO[t - o] : 0u;
        __syncthreads();
        tI[t] += xI; tO[t] += xO;
        __syncthreads();
    }
    if (t < nbuck) {
        baseI[t] = tI[t] - vI; baseO[t] = tO[t] - vO;
        curI[t]  = tI[t] - vI; curO[t]  = tO[t] - vO;
    }
}

// ---------------- bucket scatter with block-local reservation ----------------
__global__ void bucket_scatter_kernel(const int* __restrict__ src, const int* __restrict__ dst,
                                      unsigned int* __restrict__ curI, unsigned int* __restrict__ curO,
                                      int2* __restrict__ ebI, int2* __restrict__ ebO, int E)
{
    __shared__ unsigned int cI[MAXB], cO[MAXB], bI[MAXB], bO[MAXB];
    int t = threadIdx.x;
    for (int b = t; b < MAXB; b += blockDim.x) { cI[b] = 0; cO[b] = 0; }
    __syncthreads();
    int e0 = blockIdx.x * CHUNK;
    int e1 = min(E, e0 + CHUNK);
    for (int e = e0 + t; e < e1; e += blockDim.x) {
        atomicAdd(&cI[dst[e] >> BSH], 1u);
        atomicAdd(&cO[src[e] >> BSH], 1u);
    }
    __syncthreads();
    for (int b = t; b < MAXB; b += blockDim.x) {
        unsigned int n = cI[b];
        if (n) bI[b] = atomicAdd(&curI[b], n);
        cI[b] = 0;
        n = cO[b];
        if (n) bO[b] = atomicAdd(&curO[b], n);
        cO[b] = 0;
    }
    __syncthreads();
    for (int e = e0 + t; e < e1; e += blockDim.x) {
        int s = src[e], d = dst[e];
        int lb = d >> BSH;
        unsigned int p = bI[lb] + atomicAdd(&cI[lb], 1u);
        ebI[p] = make_int2(d, s);
        lb = s >> BSH;
        p = bO[lb] + atomicAdd(&cO[lb], 1u);
        ebO[p] = make_int2(s, d);
    }
}

// ---------------- fused per-bucket CSR finalize: deg + scan + rowstart/dinv + adj --------
__global__ __launch_bounds__(256) void bucket_csr_kernel(
    const int2* __restrict__ ebI, const int2* __restrict__ ebO,
    const unsigned int* __restrict__ baseI, const unsigned int* __restrict__ baseO,
    const unsigned int* __restrict__ bendI, const unsigned int* __restrict__ bendO,
    unsigned int* __restrict__ rowI, unsigned int* __restrict__ rowO,
    unsigned int* __restrict__ degI, unsigned int* __restrict__ degO,
    float* __restrict__ dinvI, float* __restrict__ dinvO,
    int* __restrict__ adjI, int* __restrict__ adjO, int N)
{
    const int2* __restrict__ eb           = blockIdx.y ? ebO : ebI;
    const unsigned int* __restrict__ base = blockIdx.y ? baseO : baseI;
    const unsigned int* __restrict__ bend = blockIdx.y ? bendO : bendI;
    unsigned int* __restrict__ row        = blockIdx.y ? rowO : rowI;
    unsigned int* __restrict__ deg        = blockIdx.y ? degO : degI;
    float* __restrict__ dinv              = blockIdx.y ? dinvO : dinvI;
    int* __restrict__ adj                 = blockIdx.y ? adjO : adjI;

    __shared__ unsigned int d[BSZ];
    __shared__ unsigned int ex[BSZ];
    __shared__ unsigned int ps[256];
    int b = blockIdx.x, t = threadIdx.x;
    int nbase = b << BSH;

    for (int i = t; i < BSZ; i += 256) d[i] = 0;
    __syncthreads();
    unsigned int lo = base[b], hi = bend[b];
    for (unsigned int i = lo + t; i < hi; i += 256)
        atomicAdd(&d[eb[i].x - nbase], 1u);
    __syncthreads();

    ps[t] = d[2 * t] + d[2 * t + 1];
    __syncthreads();
    for (int o = 1; o < 256; o <<= 1) {
        unsigned int x = (t >= o) ? ps[t - o] : 0u;
        __syncthreads();
        ps[t] += x;
        __syncthreads();
    }
    unsigned int p0 = (t > 0) ? ps[t - 1] : 0u;
    ex[2 * t]     = p0;
    ex[2 * t + 1] = p0 + d[2 * t];
    __syncthreads();

    for (int i = t; i < BSZ; i += 256) {
        int v = nbase + i;
        if (v < N) {
            unsigned int dd = d[i];
            row[v]  = lo + ex[i];
            deg[v]  = dd;
            dinv[v] = dd ? rsqrtf((float)dd) : 0.f;
        }
    }
    __syncthreads();
    for (int i = t; i < BSZ; i += 256) d[i] = lo + ex[i];
    __syncthreads();
    for (unsigned int i = lo + t; i < hi; i += 256) {
        int2 e = eb[i];
        unsigned int p = atomicAdd(&d[e.x - nbase], 1u);
        adj[p] = e.y;
    }
}

// ---------------- per-graph node counts via binary search (seg is sorted) ----------------
__global__ void seg_cnt_kernel(const int* __restrict__ seg, float* __restrict__ cnt, int N, int G)
{
    int g = blockIdx.x * blockDim.x + threadIdx.x;
    if (g >= G) return;
    int lo = 0, hi = N;
    while (lo < hi) { int m = (lo + hi) >> 1; if (seg[m] < g) lo = m + 1; else hi = m; }
    int s0 = lo;
    hi = N;
    while (lo < hi) { int m = (lo + hi) >> 1; if (seg[m] < g + 1) lo = m + 1; else hi = m; }
    cnt[g] = (float)(lo - s0);
}

// ---------------- layer2 weight prep: Wt[j][k] fp16 (pre-scaled, transposed), bcomb ------
__global__ void prep_w_kernel(const float* __restrict__ Wi, const float* __restrict__ Wr,
                              const float* __restrict__ bi, const float* __restrict__ br,
                              __half* __restrict__ Wt, float* __restrict__ bcomb)
{
    int idx = blockIdx.x * 256 + threadIdx.x;   // 128*256 elems
    if (idx < 128 * 256) {
        int j = idx >> 8, k = idx & 255;
        float w = (k < 128) ? (1.f - ALPHA) * Wi[k * 128 + j]
                            : ALPHA * Wr[(k - 128) * 128 + j];
        Wt[idx] = __float2half_rn(w);           // Wt[j*256 + k]
    }
    if (idx < 128) bcomb[idx] = (1.f - ALPHA) * bi[idx] + ALPHA * br[idx];
}

// ---------------- fused layer 1: CSR width-4 gathers + dense 4->128 fp16, relu ----------
__global__ __launch_bounds__(256) void layer1_fused_kernel(
    const unsigned int* __restrict__ rowI, const unsigned int* __restrict__ degI,
    const int* __restrict__ adjI, const float* __restrict__ dinvI,
    const unsigned int* __restrict__ rowO, const unsigned int* __restrict__ degO,
    const int* __restrict__ adjO, const float* __restrict__ dinvO,
    const float4* __restrict__ x4,
    const float* __restrict__ Wi, const float* __restrict__ bi,
    const float* __restrict__ Wr, const float* __restrict__ br,
    __half* __restrict__ h1, int N)
{
    __shared__ float wI[4][128], wO[4][128], bb[128];
    int t = threadIdx.x;
    if (t < 128) {
#pragma unroll
        for (int c = 0; c < 4; ++c) {
            wI[c][t] = (1.f - ALPHA) * Wi[c * 128 + t];
            wO[c][t] = ALPHA * Wr[c * 128 + t];
        }
        bb[t] = (1.f - ALPHA) * bi[t] + ALPHA * br[t];
    }
    __syncthreads();
    int v = blockIdx.x * 256 + t;
    if (v >= N) return;

    float4 aI = {0.f, 0.f, 0.f, 0.f};
    {
        unsigned int k = rowI[v], end = k + degI[v];
        for (; k < end; ++k) {
            int s = adjI[k];
            float w = dinvI[s];
            float4 xv = x4[s];
            aI.x += w * xv.x; aI.y += w * xv.y; aI.z += w * xv.z; aI.w += w * xv.w;
        }
        float dv = dinvI[v];
        aI.x *= dv; aI.y *= dv; aI.z *= dv; aI.w *= dv;
    }
    float4 aO = {0.f, 0.f, 0.f, 0.f};
    {
        unsigned int k = rowO[v], end = k + degO[v];
        for (; k < end; ++k) {
            int s = adjO[k];
            float w = dinvO[s];
            float4 xv = x4[s];
            aO.x += w * xv.x; aO.y += w * xv.y; aO.z += w * xv.z; aO.w += w * xv.w;
        }
        float dv = dinvO[v];
        aO.x *= dv; aO.y *= dv; aO.z *= dv; aO.w *= dv;
    }

    half8* outp = (half8*)&h1[(size_t)v * 128];
#pragma unroll
    for (int jq = 0; jq < 16; ++jq) {
        half8 o;
#pragma unroll
        for (int u = 0; u < 8; ++u) {
            int j = jq * 8 + u;
            float s = bb[j]
                    + aI.x * wI[0][j] + aI.y * wI[1][j] + aI.z * wI[2][j] + aI.w * wI[3][j]
                    + aO.x * wO[0][j] + aO.y * wO[1][j] + aO.z * wO[2][j] + aO.w * wO[3][j];
            o[u] = (_Float16)fmaxf(s, 0.f);
        }
        outp[jq] = o;
    }
}

// ---------------- fused layer 2: both-dir CSR gather -> LDS -> MFMA -> h2 fp16 -----------
// 256 threads = 16 nodes x 16 lanes. Gather phase: thread (node,lane) accumulates 8 ch
// for its node in each direction, parks fp16 in LDS [16][264] (cols 0-127 = dirI,
// 128-255 = dirO; stride 264 pads banks). MFMA phase: 4 waves x 2 col-tiles, K=256.
__global__ __launch_bounds__(256) void gather_mfma_kernel(
    const unsigned int* __restrict__ rowI, const unsigned int* __restrict__ degI,
    const int* __restrict__ adjI, const float* __restrict__ dinvI,
    const unsigned int* __restrict__ rowO, const unsigned int* __restrict__ degO,
    const int* __restrict__ adjO, const float* __restrict__ dinvO,
    const half8* __restrict__ hp,
    const __half* __restrict__ Wt,    // [128][256] pre-scaled, transposed
    const float* __restrict__ bcomb,  // [128]
    __half* __restrict__ h2, int N)
{
    __shared__ _Float16 sAB[16][264];
    int t = threadIdx.x;
    int node = t >> 4, lane = t & 15;
    int v = blockIdx.x * 16 + node;
    bool valid = v < N;

#pragma unroll
    for (int dir = 0; dir < 2; ++dir) {
        const unsigned int* __restrict__ rw = dir ? rowO : rowI;
        const unsigned int* __restrict__ dg = dir ? degO : degI;
        const int* __restrict__ adj         = dir ? adjO : adjI;
        const float* __restrict__ dinv      = dir ? dinvO : dinvI;
        float acc[8];
#pragma unroll
        for (int i = 0; i < 8; ++i) acc[i] = 0.f;
        if (valid) {
            unsigned int k = rw[v], end = k + dg[v];
            for (; k + 4 <= end; k += 4) {
                int s0 = adj[k], s1 = adj[k + 1], s2 = adj[k + 2], s3 = adj[k + 3];
                float w0 = dinv[s0], w1 = dinv[s1], w2 = dinv[s2], w3 = dinv[s3];
                half8 h0 = hp[(size_t)s0 * 16 + lane];
                half8 h1 = hp[(size_t)s1 * 16 + lane];
                half8 h2v = hp[(size_t)s2 * 16 + lane];
                half8 h3 = hp[(size_t)s3 * 16 + lane];
#pragma unroll
                for (int i = 0; i < 8; ++i)
                    acc[i] += w0 * (float)h0[i] + w1 * (float)h1[i]
                            + w2 * (float)h2v[i] + w3 * (float)h3[i];
            }
            for (; k < end; ++k) {
                int s = adj[k];
                float w = dinv[s];
                half8 hv = hp[(size_t)s * 16 + lane];
#pragma unroll
                for (int i = 0; i < 8; ++i)
                    acc[i] += w * (float)hv[i];
            }
            float dv = dinv[v];
#pragma unroll
            for (int i = 0; i < 8; ++i) acc[i] *= dv;
        }
        half8 o;
#pragma unroll
        for (int i = 0; i < 8; ++i) o[i] = (_Float16)acc[i];
        *(half8*)&sAB[node][dir * 128 + lane * 8] = o;
    }
    __syncthreads();

    // MFMA phase: wave w handles col-tiles 2w, 2w+1
    int wave = t >> 6;
    int l64 = t & 63;
    int row = l64 & 15;
    int kg  = l64 >> 4;               // 0..3
    f32x4 acc0 = {0.f, 0.f, 0.f, 0.f}, acc1 = {0.f, 0.f, 0.f, 0.f};
    int j0 = (wave * 2) * 16 + row;
    int j1 = (wave * 2 + 1) * 16 + row;
#pragma unroll
    for (int ks = 0; ks < 8; ++ks) {
        int kw = ks * 32 + kg * 8;
        half8 afrag = *(const half8*)&sAB[row][kw];
        half8 b0 = *(const half8*)&Wt[(size_t)j0 * 256 + kw];
        half8 b1 = *(const half8*)&Wt[(size_t)j1 * 256 + kw];
        acc0 = __builtin_amdgcn_mfma_f32_16x16x32_f16(afrag, b0, acc0, 0, 0, 0);
        acc1 = __builtin_amdgcn_mfma_f32_16x16x32_f16(afrag, b1, acc1, 0, 0, 0);
    }
    int v0 = blockIdx.x * 16;
    float bj0 = bcomb[j0], bj1 = bcomb[j1];
#pragma unroll
    for (int r = 0; r < 4; ++r) {
        int vr = v0 + kg * 4 + r;
        if (vr < N) {
            h2[(size_t)vr * 128 + j0] = __float2half_rn(fmaxf(acc0[r] + bj0, 0.f));
            h2[(size_t)vr * 128 + j1] = __float2half_rn(fmaxf(acc1[r] + bj1, 0.f));
        }
    }
}

// ---------------- CSR gather aggregation (layer 3), 16 lanes x half8, unroll 4 -----------
__global__ void gather128_kernel(const unsigned int* __restrict__ rowstartI,
                                 const unsigned int* __restrict__ degI,
                                 const int* __restrict__ adjI,
                                 const float* __restrict__ dinvI,
                                 const unsigned int* __restrict__ rowstartO,
                                 const unsigned int* __restrict__ degO,
                                 const int* __restrict__ adjO,
                                 const float* __restrict__ dinvO,
                                 const half8* __restrict__ hp,
                                 half8* __restrict__ outI, half8* __restrict__ outO, int N)
{
    int v = blockIdx.x * 16 + (threadIdx.x >> 4);
    if (v >= N) return;
    int lane = threadIdx.x & 15;
    const unsigned int* __restrict__ rowstart = blockIdx.y ? rowstartO : rowstartI;
    const unsigned int* __restrict__ deg      = blockIdx.y ? degO : degI;
    const int* __restrict__ adj               = blockIdx.y ? adjO : adjI;
    const float* __restrict__ dinv            = blockIdx.y ? dinvO : dinvI;
    half8* __restrict__ out                   = blockIdx.y ? outO : outI;

    unsigned int k = rowstart[v];
    unsigned int end = k + deg[v];
    float acc[8];
#pragma unroll
    for (int i = 0; i < 8; ++i) acc[i] = 0.f;

    for (; k + 4 <= end; k += 4) {
        int s0 = adj[k], s1 = adj[k + 1], s2 = adj[k + 2], s3 = adj[k + 3];
        float w0 = dinv[s0], w1 = dinv[s1], w2 = dinv[s2], w3 = dinv[s3];
        half8 h0 = hp[(size_t)s0 * 16 + lane];
        half8 h1 = hp[(size_t)s1 * 16 + lane];
        half8 h2 = hp[(size_t)s2 * 16 + lane];
        half8 h3 = hp[(size_t)s3 * 16 + lane];
#pragma unroll
        for (int i = 0; i < 8; ++i)
            acc[i] += w0 * (float)h0[i] + w1 * (float)h1[i]
                    + w2 * (float)h2[i] + w3 * (float)h3[i];
    }
    for (; k < end; ++k) {
        int s = adj[k];
        float w = dinv[s];
        half8 hv = hp[(size_t)s * 16 + lane];
#pragma unroll
        for (int i = 0; i < 8; ++i)
            acc[i] += w * (float)hv[i];
    }
    float dv = dinv[v];
    half8 o;
#pragma unroll
    for (int i = 0; i < 8; ++i) o[i] = (_Float16)(dv * acc[i]);
    out[(size_t)v * 16 + lane] = o;
}

// ---------------- pooling of fp16 aggregated features (batch_seg sorted) -----------------
#define POOL_NODES 32
__global__ void pool_kernel(const __half* __restrict__ aI, const __half* __restrict__ aO,
                            const int* __restrict__ seg,
                            float* __restrict__ poolI, float* __restrict__ poolO, int N)
{
    int j = threadIdx.x;  // 128 threads, one channel each
    int v0 = blockIdx.x * POOL_NODES;
    if (v0 >= N) return;
    int v1 = min(N, v0 + POOL_NODES);
    float sI = 0.f, sO = 0.f;
    int cur = seg[v0];
    for (int v = v0; v < v1; ++v) {
        int g = seg[v];
        if (g != cur) {
            atomicAdd(&poolI[cur * 128 + j], sI);
            atomicAdd(&poolO[cur * 128 + j], sO);
            sI = 0.f; sO = 0.f; cur = g;
        }
        sI += __half2float(aI[(size_t)v * 128 + j]);
        sO += __half2float(aO[(size_t)v * 128 + j]);
    }
    atomicAdd(&poolI[cur * 128 + j], sI);
    atomicAdd(&poolO[cur * 128 + j], sO);
}

// ---------------- final: (G,128)x2 -> (G,120) with mean ----------------
__global__ void final_kernel(const float* __restrict__ poolI, const float* __restrict__ poolO,
                             const float* __restrict__ cnt,
                             const float* __restrict__ Wo, const float* __restrict__ bo,
                             const float* __restrict__ Wor, const float* __restrict__ bor,
                             float* __restrict__ out, int G)
{
    int g = blockIdx.x;
    int j = threadIdx.x;  // 120 threads
    if (g >= G || j >= 120) return;
    float acc = 0.f;
    for (int k = 0; k < 128; ++k) {
        acc += poolI[g * 128 + k] * ((1.f - ALPHA) * Wo[k * 120 + j])
             + poolO[g * 128 + k] * (ALPHA * Wor[k * 120 + j]);
    }
    float c = cnt[g];
    float bcomb = (1.f - ALPHA) * bo[j] + ALPHA * bor[j];
    out[g * 120 + j] = (c > 0.f) ? (acc / c + bcomb) : 0.f;
}

extern "C" void kernel_launch(void* const* d_in, const int* in_sizes, int n_in,
                              void* d_out, int out_size, void* d_ws, size_t ws_size,
                              hipStream_t stream)
{
    const float* x      = (const float*)d_in[0];
    const int*   ei     = (const int*)d_in[1];
    const int*   seg    = (const int*)d_in[2];
    const float* W_in   = (const float*)d_in[3];
    const float* b_in   = (const float*)d_in[4];
    const float* W_in_r = (const float*)d_in[5];
    const float* b_in_r = (const float*)d_in[6];
    const float* W_mid  = (const float*)d_in[7];
    const float* b_mid  = (const float*)d_in[8];
    const float* W_mid_r= (const float*)d_in[9];
    const float* b_mid_r= (const float*)d_in[10];
    const float* W_out  = (const float*)d_in[11];
    const float* b_out  = (const float*)d_in[12];
    const float* W_out_r= (const float*)d_in[13];
    const float* b_out_r= (const float*)d_in[14];

    const int N = in_sizes[0] / 4;
    const int E = in_sizes[1] / 2;
    const int G = out_size / 120;
    const int* src = ei;
    const int* dst = ei + E;
    const int NBUCK = ceil_div(N, BSZ);      // <= 512

    // -------- workspace layout (4-byte units) --------
    char* wsb = (char*)d_ws;
    size_t off = 0;
    auto alloc = [&](size_t elems) { void* p = wsb + off * 4; off += elems; return p; };

    unsigned int* bhI   = (unsigned int*)alloc(MAXB);     // zeroed
    unsigned int* bhO   = (unsigned int*)alloc(MAXB);     // zeroed
    float*        poolI = (float*)alloc((size_t)G * 128); // zeroed (atomic targets)
    float*        poolO = (float*)alloc((size_t)G * 128); // zeroed
    size_t zero_elems = off;
    float*        cnt   = (float*)alloc(G);               // fully written by seg_cnt
    unsigned int* baseI = (unsigned int*)alloc(MAXB);
    unsigned int* baseO = (unsigned int*)alloc(MAXB);
    unsigned int* curI  = (unsigned int*)alloc(MAXB);
    unsigned int* curO  = (unsigned int*)alloc(MAXB);
    unsigned int* degI  = (unsigned int*)alloc(N);
    unsigned int* degO  = (unsigned int*)alloc(N);
    float*        dinvI = (float*)alloc(N);
    float*        dinvO = (float*)alloc(N);
    unsigned int* rowI  = (unsigned int*)alloc(N);        // exclusive row starts
    unsigned int* rowO  = (unsigned int*)alloc(N);
    int*          adjI  = (int*)alloc(E);
    int*          adjO  = (int*)alloc(E);
    __half*       Wt    = (__half*)alloc(128 * 256 / 2);  // 32768 halves
    float*        bcomb = (float*)alloc(128);
    off = (off + 3) & ~(size_t)3;                         // 16B align
    __half* hbuf = (__half*)alloc((size_t)N * 64);        // h1 / h2 fp16 (N*128 halves)
    __half* aggI = (__half*)alloc((size_t)N * 64);        // fp16 agg in-direction (layer 3)
    __half* aggO = (__half*)alloc((size_t)N * 64);        // fp16 agg out-direction (layer 3)
    (void)ws_size;

    // Bucketed edge buffers alias agg buffers (dead until layer-3 gather writes them).
    int2* ebI = (int2*)aggI;
    int2* ebO = (int2*)aggO;

    hipMemsetAsync(d_ws, 0, zero_elems * 4, stream);

    const int T = 256;
    // ---- binned CSR build ----
    hist_kernel<<<ceil_div(E, T * 16), T, 0, stream>>>(src, dst, bhI, bhO, E, NBUCK);
    bucket_base_kernel<<<1, MAXB, 0, stream>>>(bhI, bhO, baseI, baseO, curI, curO, NBUCK);
    bucket_scatter_kernel<<<ceil_div(E, CHUNK), T, 0, stream>>>(src, dst, curI, curO, ebI, ebO, E);
    bucket_csr_kernel<<<dim3(NBUCK, 2), T, 0, stream>>>(ebI, ebO, baseI, baseO, curI, curO,
                                                        rowI, rowO, degI, degO,
                                                        dinvI, dinvO, adjI, adjO, N);
    seg_cnt_kernel<<<ceil_div(G, T), T, 0, stream>>>(seg, cnt, N, G);
    prep_w_kernel<<<128, 256, 0, stream>>>(W_mid, W_mid_r, b_mid, b_mid_r, Wt, bcomb);

    // ---- layer 1: fused CSR-4 gathers + dense 4->128 (fp16 out) ----
    layer1_fused_kernel<<<ceil_div(N, T), T, 0, stream>>>(
        rowI, degI, adjI, dinvI, rowO, degO, adjO, dinvO,
        (const float4*)x, W_in, b_in, W_in_r, b_in_r, hbuf, N);
    // ---- layer 2: fused both-dir gather + MFMA GEMM -> h2 (fp16, in place of h1 after read)
    //      reads hbuf (h1), writes aggI-free path directly to hbuf? No: read+write same buf
    //      would race across blocks; write h2 into a distinct buffer then swap pointers.
    gather_mfma_kernel<<<ceil_div(N, 16), 256, 0, stream>>>(
        rowI, degI, adjI, dinvI, rowO, degO, adjO, dinvO,
        (const half8*)hbuf, Wt, bcomb, aggI, N);   // h2 -> aggI buffer (25.6 MB)
    // ---- layer 3: gather both dirs from h2(=aggI), then pool + final projection ----
    gather128_kernel<<<dim3(ceil_div(N, 16), 2), 256, 0, stream>>>(
        rowI, degI, adjI, dinvI, rowO, degO, adjO, dinvO,
        (const half8*)aggI, (half8*)hbuf, (half8*)aggO, N);  // aggI3 -> hbuf, aggO3 -> aggO
    pool_kernel<<<ceil_div(N, POOL_NODES), 128, 0, stream>>>(
        hbuf, aggO, seg, poolI, poolO, N);
    final_kernel<<<G, 128, 0, stream>>>(poolI, poolO, cnt,
                                        W_out, b_out, W_out_r, b_out_r, (float*)d_out, G);
}